// Round 6
// baseline (700.592 us; speedup 1.0000x reference)
//
#include <hip/hip_runtime.h>
#include <hip/hip_cooperative_groups.h>

namespace cg = cooperative_groups;

// incepLayer, float32 in/out. out = concat([h, f1, f2, f3]); f_k are alpha-
// mixes of P^k h, P = weighted segment_sum over edges, e = d[src]*d[dst].
// Linearity => 3 gather passes over {h, Ph, P2h}; final phase fuses combine.
// All phases in ONE cooperative kernel (grid.sync between) to kill ~15 us
// per-dispatch overhead observed in rounds 3-5.

#define NN   40000
#define NE   640000
#define CAP  64     // in-degree ~ Poisson(16); P(>64) ~ 1e-17
#define GRID 1024
#define BLK  256

__device__ inline unsigned short f2h(float f) {
    _Float16 h = (_Float16)f;
    return *(unsigned short*)&h;
}
__device__ inline float h2f(unsigned short u) {
    _Float16 h = *(_Float16*)&u;
    return (float)h;
}
__device__ inline unsigned short f2bf(float f) {  // round-to-nearest-even
    unsigned int x = __float_as_uint(f);
    x += 0x7fffu + ((x >> 16) & 1u);
    return (unsigned short)(x >> 16);
}
__device__ inline unsigned int pack_bf2(float x, float y) {
    return ((unsigned int)f2bf(y) << 16) | (unsigned int)f2bf(x);
}
__device__ inline float bflo(unsigned int u) { return __uint_as_float(u << 16); }
__device__ inline float bfhi(unsigned int u) { return __uint_as_float(u & 0xffff0000u); }

// ---- core gather: one wave per node, bf16 pair per lane, 8 loads in flight -
__device__ inline float2 gather_node(
    const unsigned int* __restrict__ feat,   // bf16 rows, 64 words/row
    const int* __restrict__ counts, const unsigned int* __restrict__ buck,
    int v, int lane) {
    int cnt = counts[v];
    if (cnt > CAP) cnt = CAP;
    unsigned int myw = buck[(size_t)v * CAP + lane];  // lane j holds word j
    if (lane >= cnt) myw = 0u;                        // w = 0.0, src = 0
    float ax = 0.f, ay = 0.f, bx = 0.f, by = 0.f;
    float cx = 0.f, cy = 0.f, dx = 0.f, dy = 0.f;
    for (int j = 0; j < cnt; j += 8) {
        unsigned int u0 = __shfl(myw, j + 0), u1 = __shfl(myw, j + 1);
        unsigned int u2 = __shfl(myw, j + 2), u3 = __shfl(myw, j + 3);
        unsigned int u4 = __shfl(myw, j + 4), u5 = __shfl(myw, j + 5);
        unsigned int u6 = __shfl(myw, j + 6), u7 = __shfl(myw, j + 7);
        unsigned int f0 = feat[(size_t)(u0 & 0xffffu) * 64 + lane];
        unsigned int f1 = feat[(size_t)(u1 & 0xffffu) * 64 + lane];
        unsigned int f2 = feat[(size_t)(u2 & 0xffffu) * 64 + lane];
        unsigned int f3 = feat[(size_t)(u3 & 0xffffu) * 64 + lane];
        unsigned int f4 = feat[(size_t)(u4 & 0xffffu) * 64 + lane];
        unsigned int f5 = feat[(size_t)(u5 & 0xffffu) * 64 + lane];
        unsigned int f6 = feat[(size_t)(u6 & 0xffffu) * 64 + lane];
        unsigned int f7 = feat[(size_t)(u7 & 0xffffu) * 64 + lane];
        float w0 = h2f((unsigned short)(u0 >> 16));
        float w1 = h2f((unsigned short)(u1 >> 16));
        float w2 = h2f((unsigned short)(u2 >> 16));
        float w3 = h2f((unsigned short)(u3 >> 16));
        float w4 = h2f((unsigned short)(u4 >> 16));
        float w5 = h2f((unsigned short)(u5 >> 16));
        float w6 = h2f((unsigned short)(u6 >> 16));
        float w7 = h2f((unsigned short)(u7 >> 16));
        ax = fmaf(w0, bflo(f0), ax); ay = fmaf(w0, bfhi(f0), ay);
        bx = fmaf(w1, bflo(f1), bx); by = fmaf(w1, bfhi(f1), by);
        cx = fmaf(w2, bflo(f2), cx); cy = fmaf(w2, bfhi(f2), cy);
        dx = fmaf(w3, bflo(f3), dx); dy = fmaf(w3, bfhi(f3), dy);
        ax = fmaf(w4, bflo(f4), ax); ay = fmaf(w4, bfhi(f4), ay);
        bx = fmaf(w5, bflo(f5), bx); by = fmaf(w5, bfhi(f5), by);
        cx = fmaf(w6, bflo(f6), cx); cy = fmaf(w6, bfhi(f6), cy);
        dx = fmaf(w7, bflo(f7), dx); dy = fmaf(w7, bfhi(f7), dy);
    }
    return make_float2((ax + bx) + (cx + dx), (ay + by) + (cy + dy));
}

// ======================= single cooperative kernel ==========================
__global__ __launch_bounds__(BLK) void fused_k(
    const float* __restrict__ h, const float* __restrict__ deg,
    const float* __restrict__ alphas,
    const int* __restrict__ src, const int* __restrict__ dst,
    float* __restrict__ out,
    int* __restrict__ counts, unsigned int* __restrict__ buck,
    unsigned int* __restrict__ hb, unsigned int* __restrict__ p1b,
    unsigned int* __restrict__ p2b) {
    cg::grid_group grid = cg::this_grid();
    const int tid  = blockIdx.x * BLK + threadIdx.x;
    const int nthr = GRID * BLK;                 // 262144
    const int lane = threadIdx.x & 63;
    const int wid  = blockIdx.x * (BLK / 64) + (threadIdx.x >> 6);
    const int nw   = GRID * (BLK / 64);          // 4096 waves

    // -- phase 0: zero counts; cvt h->hb (bf16); copy h into out section 0 --
    if (tid < NN) counts[tid] = 0;
    for (int i = tid; i < NN * 64; i += nthr) {
        float2 f = *(const float2*)(h + (size_t)i * 2);
        hb[i] = pack_bf2(f.x, f.y);
        int v = i >> 6, w = i & 63;
        *(float2*)(out + (size_t)v * 512 + w * 2) = f;
    }
    grid.sync();

    // -- phase 1: build per-dst buckets: f16(w)<<16 | src(16b) --------------
    for (int e = tid; e < NE; e += nthr) {
        int s = src[e];
        int v = dst[e];
        int slot = atomicAdd(&counts[v], 1);
        if (slot < CAP)
            buck[v * CAP + slot] =
                ((unsigned int)f2h(deg[s] * deg[v]) << 16) | (unsigned int)s;
    }
    grid.sync();

    // -- phase 2: P^1 = P hb ------------------------------------------------
    for (int v = wid; v < NN; v += nw) {
        float2 a = gather_node(hb, counts, buck, v, lane);
        p1b[(size_t)v * 64 + lane] = pack_bf2(a.x, a.y);
    }
    grid.sync();

    // -- phase 3: P^2 = P p1b -----------------------------------------------
    for (int v = wid; v < NN; v += nw) {
        float2 a = gather_node(p1b, counts, buck, v, lane);
        p2b[(size_t)v * 64 + lane] = pack_bf2(a.x, a.y);
    }
    grid.sync();

    // -- phase 4: P^3 gather + alpha combine, write out sections 1..3 -------
    float a0 = alphas[0], a1 = alphas[1], a2 = alphas[2];
    float a3 = alphas[3], a4 = alphas[4], a5 = alphas[5];
    float c1p = a0, c1h = 1.f - a0;
    float c2pp = a2 * a1;
    float c2p  = a2 * (1.f - a1) + (1.f - a2) * a1;
    float c2h  = (1.f - a2) * (1.f - a1);
    float s2pp = a4 * a3;
    float s2p  = a4 * (1.f - a3) + (1.f - a4) * a3;
    float s2h  = (1.f - a4) * (1.f - a3);
    float c3ppp = a5 * s2pp;
    float c3pp  = a5 * s2p + (1.f - a5) * s2pp;
    float c3p   = a5 * s2h + (1.f - a5) * s2p;
    float c3h   = (1.f - a5) * s2h;

    for (int v = wid; v < NN; v += nw) {
        float2 p3 = gather_node(p2b, counts, buck, v, lane);
        int i2 = lane * 2;
        float2 hf = *(const float2*)(h + (size_t)v * 128 + i2);
        unsigned int u1 = p1b[(size_t)v * 64 + lane];
        unsigned int u2 = p2b[(size_t)v * 64 + lane];
        float q1x = bflo(u1), q1y = bfhi(u1);
        float q2x = bflo(u2), q2y = bfhi(u2);
        float2 r1, r2, r3;
        r1.x = c1p * q1x + c1h * hf.x;
        r1.y = c1p * q1y + c1h * hf.y;
        r2.x = c2pp * q2x + c2p * q1x + c2h * hf.x;
        r2.y = c2pp * q2y + c2p * q1y + c2h * hf.y;
        r3.x = c3ppp * p3.x + c3pp * q2x + c3p * q1x + c3h * hf.x;
        r3.y = c3ppp * p3.y + c3pp * q2y + c3p * q1y + c3h * hf.y;
        float* o = out + (size_t)v * 512;
        *(float2*)(o + 128 + i2) = r1;
        *(float2*)(o + 256 + i2) = r2;
        *(float2*)(o + 384 + i2) = r3;
    }
}

// ==================== fallback multi-launch path (round-5) ==================
__global__ __launch_bounds__(256) void build_buckets_k(
    const int* __restrict__ src, const int* __restrict__ dst,
    const float* __restrict__ deg,
    int* __restrict__ counts, unsigned int* __restrict__ buck) {
    int e = blockIdx.x * 256 + threadIdx.x;
    if (e >= NE) return;
    int s = src[e];
    int v = dst[e];
    int slot = atomicAdd(&counts[v], 1);
    if (slot < CAP)
        buck[v * CAP + slot] =
            ((unsigned int)f2h(deg[s] * deg[v]) << 16) | (unsigned int)s;
}

__global__ __launch_bounds__(256) void cvt_h_k(
    const float* __restrict__ h, unsigned int* __restrict__ hb,
    float* __restrict__ out) {
    int i = blockIdx.x * 256 + threadIdx.x;
    if (i >= NN * 64) return;
    float2 f = *(const float2*)(h + (size_t)i * 2);
    hb[i] = pack_bf2(f.x, f.y);
    int v = i >> 6, w = i & 63;
    *(float2*)(out + (size_t)v * 512 + w * 2) = f;
}

__global__ __launch_bounds__(256) void agg_k(
    const unsigned int* __restrict__ feat,
    const int* __restrict__ counts, const unsigned int* __restrict__ buck,
    unsigned int* __restrict__ outf) {
    int gid  = blockIdx.x * 256 + threadIdx.x;
    int v    = gid >> 6;
    int lane = gid & 63;
    if (v >= NN) return;
    float2 acc = gather_node(feat, counts, buck, v, lane);
    outf[(size_t)v * 64 + lane] = pack_bf2(acc.x, acc.y);
}

__global__ __launch_bounds__(256) void agg3_fused_k(
    const unsigned int* __restrict__ p2b, const float* __restrict__ h,
    const unsigned int* __restrict__ p1b,
    const int* __restrict__ counts, const unsigned int* __restrict__ buck,
    const float* __restrict__ alphas, float* __restrict__ out) {
    int gid  = blockIdx.x * 256 + threadIdx.x;
    int v    = gid >> 6;
    int lane = gid & 63;
    if (v >= NN) return;
    float2 p3 = gather_node(p2b, counts, buck, v, lane);
    float a0 = alphas[0], a1 = alphas[1], a2 = alphas[2];
    float a3 = alphas[3], a4 = alphas[4], a5 = alphas[5];
    float c1p = a0, c1h = 1.f - a0;
    float c2pp = a2 * a1;
    float c2p  = a2 * (1.f - a1) + (1.f - a2) * a1;
    float c2h  = (1.f - a2) * (1.f - a1);
    float s2pp = a4 * a3;
    float s2p  = a4 * (1.f - a3) + (1.f - a4) * a3;
    float s2h  = (1.f - a4) * (1.f - a3);
    float c3ppp = a5 * s2pp;
    float c3pp  = a5 * s2p + (1.f - a5) * s2pp;
    float c3p   = a5 * s2h + (1.f - a5) * s2p;
    float c3h   = (1.f - a5) * s2h;
    int i2 = lane * 2;
    float2 hf = *(const float2*)(h + (size_t)v * 128 + i2);
    unsigned int u1 = p1b[(size_t)v * 64 + lane];
    unsigned int u2 = p2b[(size_t)v * 64 + lane];
    float q1x = bflo(u1), q1y = bfhi(u1);
    float q2x = bflo(u2), q2y = bfhi(u2);
    float2 r1, r2, r3;
    r1.x = c1p * q1x + c1h * hf.x;
    r1.y = c1p * q1y + c1h * hf.y;
    r2.x = c2pp * q2x + c2p * q1x + c2h * hf.x;
    r2.y = c2pp * q2y + c2p * q1y + c2h * hf.y;
    r3.x = c3ppp * p3.x + c3pp * q2x + c3p * q1x + c3h * hf.x;
    r3.y = c3ppp * p3.y + c3pp * q2y + c3p * q1y + c3h * hf.y;
    float* o = out + (size_t)v * 512;
    *(float2*)(o + 128 + i2) = r1;
    *(float2*)(o + 256 + i2) = r2;
    *(float2*)(o + 384 + i2) = r3;
}

extern "C" void kernel_launch(void* const* d_in, const int* in_sizes, int n_in,
                              void* d_out, int out_size, void* d_ws, size_t ws_size,
                              hipStream_t stream) {
    const float* h      = (const float*)d_in[0];
    const float* deg    = (const float*)d_in[1];
    const float* alphas = (const float*)d_in[2];
    const int*   src    = (const int*)d_in[3];
    const int*   dst    = (const int*)d_in[4];
    float* out = (float*)d_out;

    // ws: counts 160,000 | buck 10,240,000 | hb 10,240,000 |
    //     p1b 10,240,000 | p2b 10,240,000   => 41,120,000 B total
    char* ws = (char*)d_ws;
    int*          counts = (int*)(ws + 0);
    unsigned int* buck   = (unsigned int*)(ws + 160000);
    unsigned int* hb     = (unsigned int*)(ws + 10400000);
    unsigned int* p1b    = (unsigned int*)(ws + 20640000);
    unsigned int* p2b    = (unsigned int*)(ws + 30880000);

    void* args[] = {(void*)&h,   (void*)&deg, (void*)&alphas, (void*)&src,
                    (void*)&dst, (void*)&out, (void*)&counts, (void*)&buck,
                    (void*)&hb,  (void*)&p1b, (void*)&p2b};
    hipError_t err = hipLaunchCooperativeKernel((const void*)fused_k,
                                                dim3(GRID), dim3(BLK),
                                                args, 0, stream);
    if (err != hipSuccess) {
        // fallback: multi-launch path (identical math)
        hipMemsetAsync(counts, 0, NN * sizeof(int), stream);
        build_buckets_k<<<NE / 256, 256, 0, stream>>>(src, dst, deg, counts, buck);
        cvt_h_k<<<(NN * 64 + 255) / 256, 256, 0, stream>>>(h, hb, out);
        agg_k<<<NN / 4, 256, 0, stream>>>(hb,  counts, buck, p1b);
        agg_k<<<NN / 4, 256, 0, stream>>>(p1b, counts, buck, p2b);
        agg3_fused_k<<<NN / 4, 256, 0, stream>>>(p2b, h, p1b, counts, buck,
                                                 alphas, out);
    }
}

// Round 7
// 217.763 us; speedup vs baseline: 3.2172x; 3.2172x over previous
//
#include <hip/hip_runtime.h>

// incepLayer, float32 in/out. out = concat([h, f1, f2, f3]); f_k are alpha-
// mixes of P^k h, P = weighted segment_sum over edges, e = d[src]*d[dst].
// Linearity => 3 gather passes over {h, Ph, P2h}. Multi-launch (cooperative
// grid.sync measured 3x slower on gfx950 — round 6). 5 dispatches:
//   init (zero counts + h->bf16 + out sec0), build buckets,
//   agg1 (P^1), agg2 (P^2 + emit sec1,sec2), agg3 (P^3 + emit sec3).

#define NN  40000
#define NE  640000
#define CAP 64   // in-degree ~ Poisson(16); P(>64) ~ 1e-17

__device__ inline unsigned short f2h(float f) {
    _Float16 h = (_Float16)f;
    return *(unsigned short*)&h;
}
__device__ inline float h2f(unsigned short u) {
    _Float16 h = *(_Float16*)&u;
    return (float)h;
}
__device__ inline unsigned short f2bf(float f) {  // round-to-nearest-even
    unsigned int x = __float_as_uint(f);
    x += 0x7fffu + ((x >> 16) & 1u);
    return (unsigned short)(x >> 16);
}
__device__ inline unsigned int pack_bf2(float x, float y) {
    return ((unsigned int)f2bf(y) << 16) | (unsigned int)f2bf(x);
}
__device__ inline float bflo(unsigned int u) { return __uint_as_float(u << 16); }
__device__ inline float bfhi(unsigned int u) { return __uint_as_float(u & 0xffff0000u); }

// ---- init: zero counts; h -> bf16 rows; copy h into out section 0 ----------
__global__ __launch_bounds__(256) void init_k(
    const float* __restrict__ h, unsigned int* __restrict__ hb,
    int* __restrict__ counts, float* __restrict__ out) {
    int i = blockIdx.x * 256 + threadIdx.x;     // one uint (2 dims) per thread
    if (i < NN) counts[i] = 0;
    if (i >= NN * 64) return;
    float2 f = *(const float2*)(h + (size_t)i * 2);
    hb[i] = pack_bf2(f.x, f.y);
    int v = i >> 6, w = i & 63;
    *(float2*)(out + (size_t)v * 512 + w * 2) = f;
}

// ---- build per-dst buckets: one uint per edge = f16(w)<<16 | src(16b) ------
__global__ __launch_bounds__(256) void build_buckets_k(
    const int* __restrict__ src, const int* __restrict__ dst,
    const float* __restrict__ deg,
    int* __restrict__ counts, unsigned int* __restrict__ buck) {
    int e = blockIdx.x * 256 + threadIdx.x;
    if (e >= NE) return;
    int s = src[e];
    int v = dst[e];
    int slot = atomicAdd(&counts[v], 1);
    if (slot < CAP)
        buck[v * CAP + slot] =
            ((unsigned int)f2h(deg[s] * deg[v]) << 16) | (unsigned int)s;
}

// ---- core gather: one wave per node, bf16 pair per lane, 8 loads in flight -
__device__ inline float2 gather_node(
    const unsigned int* __restrict__ feat,   // bf16 rows, 64 words/row
    const int* __restrict__ counts, const unsigned int* __restrict__ buck,
    int v, int lane) {
    int cnt = counts[v];
    if (cnt > CAP) cnt = CAP;
    unsigned int myw = buck[(size_t)v * CAP + lane];  // lane j holds word j
    if (lane >= cnt) myw = 0u;                        // w = 0.0, src = 0
    float ax = 0.f, ay = 0.f, bx = 0.f, by = 0.f;
    float cx = 0.f, cy = 0.f, dx = 0.f, dy = 0.f;
    for (int j = 0; j < cnt; j += 8) {
        unsigned int u0 = __shfl(myw, j + 0), u1 = __shfl(myw, j + 1);
        unsigned int u2 = __shfl(myw, j + 2), u3 = __shfl(myw, j + 3);
        unsigned int u4 = __shfl(myw, j + 4), u5 = __shfl(myw, j + 5);
        unsigned int u6 = __shfl(myw, j + 6), u7 = __shfl(myw, j + 7);
        unsigned int f0 = feat[(size_t)(u0 & 0xffffu) * 64 + lane];
        unsigned int f1 = feat[(size_t)(u1 & 0xffffu) * 64 + lane];
        unsigned int f2 = feat[(size_t)(u2 & 0xffffu) * 64 + lane];
        unsigned int f3 = feat[(size_t)(u3 & 0xffffu) * 64 + lane];
        unsigned int f4 = feat[(size_t)(u4 & 0xffffu) * 64 + lane];
        unsigned int f5 = feat[(size_t)(u5 & 0xffffu) * 64 + lane];
        unsigned int f6 = feat[(size_t)(u6 & 0xffffu) * 64 + lane];
        unsigned int f7 = feat[(size_t)(u7 & 0xffffu) * 64 + lane];
        float w0 = h2f((unsigned short)(u0 >> 16));
        float w1 = h2f((unsigned short)(u1 >> 16));
        float w2 = h2f((unsigned short)(u2 >> 16));
        float w3 = h2f((unsigned short)(u3 >> 16));
        float w4 = h2f((unsigned short)(u4 >> 16));
        float w5 = h2f((unsigned short)(u5 >> 16));
        float w6 = h2f((unsigned short)(u6 >> 16));
        float w7 = h2f((unsigned short)(u7 >> 16));
        ax = fmaf(w0, bflo(f0), ax); ay = fmaf(w0, bfhi(f0), ay);
        bx = fmaf(w1, bflo(f1), bx); by = fmaf(w1, bfhi(f1), by);
        cx = fmaf(w2, bflo(f2), cx); cy = fmaf(w2, bfhi(f2), cy);
        dx = fmaf(w3, bflo(f3), dx); dy = fmaf(w3, bfhi(f3), dy);
        ax = fmaf(w4, bflo(f4), ax); ay = fmaf(w4, bfhi(f4), ay);
        bx = fmaf(w5, bflo(f5), bx); by = fmaf(w5, bfhi(f5), by);
        cx = fmaf(w6, bflo(f6), cx); cy = fmaf(w6, bfhi(f6), cy);
        dx = fmaf(w7, bflo(f7), dx); dy = fmaf(w7, bfhi(f7), dy);
    }
    return make_float2((ax + bx) + (cx + dx), (ay + by) + (cy + dy));
}

// ---- pass 1: P^1 = P hb -> p1b (bf16) --------------------------------------
__global__ __launch_bounds__(256) void agg1_k(
    const unsigned int* __restrict__ hb,
    const int* __restrict__ counts, const unsigned int* __restrict__ buck,
    unsigned int* __restrict__ p1b) {
    int gid  = blockIdx.x * 256 + threadIdx.x;
    int v    = gid >> 6;
    int lane = gid & 63;
    if (v >= NN) return;
    float2 a = gather_node(hb, counts, buck, v, lane);
    p1b[(size_t)v * 64 + lane] = pack_bf2(a.x, a.y);
}

// ---- pass 2: P^2 = P p1b -> p2b; also emit out sections 1 and 2 ------------
__global__ __launch_bounds__(256) void agg2_k(
    const unsigned int* __restrict__ p1b, const float* __restrict__ h,
    const int* __restrict__ counts, const unsigned int* __restrict__ buck,
    const float* __restrict__ alphas,
    unsigned int* __restrict__ p2b, float* __restrict__ out) {
    int gid  = blockIdx.x * 256 + threadIdx.x;
    int v    = gid >> 6;
    int lane = gid & 63;
    if (v >= NN) return;
    float2 p2 = gather_node(p1b, counts, buck, v, lane);   // f32 accumulator
    p2b[(size_t)v * 64 + lane] = pack_bf2(p2.x, p2.y);

    float a0 = alphas[0], a1 = alphas[1], a2 = alphas[2];
    float c1p = a0, c1h = 1.f - a0;
    float c2pp = a2 * a1;
    float c2p  = a2 * (1.f - a1) + (1.f - a2) * a1;
    float c2h  = (1.f - a2) * (1.f - a1);

    int i2 = lane * 2;
    float2 hf = *(const float2*)(h + (size_t)v * 128 + i2);
    unsigned int u1 = p1b[(size_t)v * 64 + lane];
    float q1x = bflo(u1), q1y = bfhi(u1);

    float2 r1, r2;
    r1.x = c1p * q1x + c1h * hf.x;
    r1.y = c1p * q1y + c1h * hf.y;
    r2.x = c2pp * p2.x + c2p * q1x + c2h * hf.x;
    r2.y = c2pp * p2.y + c2p * q1y + c2h * hf.y;
    float* o = out + (size_t)v * 512;
    *(float2*)(o + 128 + i2) = r1;
    *(float2*)(o + 256 + i2) = r2;
}

// ---- pass 3: P^3 = P p2b; emit out section 3 -------------------------------
__global__ __launch_bounds__(256) void agg3_k(
    const unsigned int* __restrict__ p2b, const float* __restrict__ h,
    const unsigned int* __restrict__ p1b,
    const int* __restrict__ counts, const unsigned int* __restrict__ buck,
    const float* __restrict__ alphas, float* __restrict__ out) {
    int gid  = blockIdx.x * 256 + threadIdx.x;
    int v    = gid >> 6;
    int lane = gid & 63;
    if (v >= NN) return;
    float2 p3 = gather_node(p2b, counts, buck, v, lane);

    float a3 = alphas[3], a4 = alphas[4], a5 = alphas[5];
    float s2pp = a4 * a3;
    float s2p  = a4 * (1.f - a3) + (1.f - a4) * a3;
    float s2h  = (1.f - a4) * (1.f - a3);
    float c3ppp = a5 * s2pp;
    float c3pp  = a5 * s2p + (1.f - a5) * s2pp;
    float c3p   = a5 * s2h + (1.f - a5) * s2p;
    float c3h   = (1.f - a5) * s2h;

    int i2 = lane * 2;
    float2 hf = *(const float2*)(h + (size_t)v * 128 + i2);
    unsigned int u1 = p1b[(size_t)v * 64 + lane];
    unsigned int u2 = p2b[(size_t)v * 64 + lane];
    float q1x = bflo(u1), q1y = bfhi(u1);
    float q2x = bflo(u2), q2y = bfhi(u2);

    float2 r3;
    r3.x = c3ppp * p3.x + c3pp * q2x + c3p * q1x + c3h * hf.x;
    r3.y = c3ppp * p3.y + c3pp * q2y + c3p * q1y + c3h * hf.y;
    *(float2*)(out + (size_t)v * 512 + 384 + i2) = r3;
}

extern "C" void kernel_launch(void* const* d_in, const int* in_sizes, int n_in,
                              void* d_out, int out_size, void* d_ws, size_t ws_size,
                              hipStream_t stream) {
    const float* h      = (const float*)d_in[0];
    const float* deg    = (const float*)d_in[1];
    const float* alphas = (const float*)d_in[2];
    const int*   src    = (const int*)d_in[3];
    const int*   dst    = (const int*)d_in[4];
    float* out = (float*)d_out;

    // ws: counts 160,000 | buck 10,240,000 | hb 10,240,000 |
    //     p1b 10,240,000 | p2b 10,240,000   => 41,120,000 B total
    char* ws = (char*)d_ws;
    int*          counts = (int*)(ws + 0);
    unsigned int* buck   = (unsigned int*)(ws + 160000);
    unsigned int* hb     = (unsigned int*)(ws + 10400000);
    unsigned int* p1b    = (unsigned int*)(ws + 20640000);
    unsigned int* p2b    = (unsigned int*)(ws + 30880000);

    init_k<<<(NN * 64 + 255) / 256, 256, 0, stream>>>(h, hb, counts, out);
    build_buckets_k<<<NE / 256, 256, 0, stream>>>(src, dst, deg, counts, buck);
    agg1_k<<<NN / 4, 256, 0, stream>>>(hb, counts, buck, p1b);
    agg2_k<<<NN / 4, 256, 0, stream>>>(p1b, h, counts, buck, alphas, p2b, out);
    agg3_k<<<NN / 4, 256, 0, stream>>>(p2b, h, p1b, counts, buck, alphas, out);
}